// Round 4
// baseline (236.321 us; speedup 1.0000x reference)
//
#include <hip/hip_runtime.h>
#include <cstdint>

#define BB 8
#define SQ 1024
#define HH 1024
#define NH 16
#define HD 64

typedef __attribute__((ext_vector_type(4))) float f32x4;
typedef __attribute__((ext_vector_type(8))) __bf16 bf16x8;
typedef __attribute__((ext_vector_type(8))) unsigned short u16x8;
typedef __attribute__((ext_vector_type(4))) unsigned short u16x4;

__device__ __forceinline__ unsigned short f2bf(float f){
  uint32_t u = __builtin_bit_cast(uint32_t, f);
  u += 0x7FFFu + ((u >> 16) & 1u);
  return (unsigned short)(u >> 16);
}

__device__ __forceinline__ void gload_lds16(const void* g, void* l){
  __builtin_amdgcn_global_load_lds((__attribute__((address_space(1))) void*)g,
                                   (__attribute__((address_space(3))) void*)l,
                                   16, 0, 0);
}

// ---------------- convert hidden_states fp32 -> bf16 ----------------
__global__ __launch_bounds__(256) void k_convert_x(const float* __restrict__ x,
                                                   unsigned short* __restrict__ xb){
  int i = blockIdx.x * 256 + threadIdx.x;
  const f32x4* xv = (const f32x4*)x;
  f32x4 a = xv[2*i], b = xv[2*i+1];
  u16x8 o;
  o[0]=f2bf(a[0]); o[1]=f2bf(a[1]); o[2]=f2bf(a[2]); o[3]=f2bf(a[3]);
  o[4]=f2bf(b[0]); o[5]=f2bf(b[1]); o[6]=f2bf(b[2]); o[7]=f2bf(b[3]);
  ((u16x8*)xb)[i] = o;
}

// ---------------- transpose + convert W -> Wt bf16 [n][k] ----------------
__global__ __launch_bounds__(256) void k_wt(const float* __restrict__ Wq,
                                            const float* __restrict__ Wk,
                                            const float* __restrict__ Wv,
                                            unsigned short* __restrict__ wt){
  __shared__ float t[32][33];
  int p = blockIdx.z;
  const float* W = (p==0)?Wq:((p==1)?Wk:Wv);
  int n0 = blockIdx.x*32, k0 = blockIdx.y*32;
  int tx = threadIdx.x, ty = threadIdx.y;
  #pragma unroll
  for(int j=0;j<32;j+=8) t[ty+j][tx] = W[(size_t)(k0+ty+j)*HH + n0+tx];
  __syncthreads();
  unsigned short* o = wt + (size_t)p*HH*HH;
  #pragma unroll
  for(int j=0;j<32;j+=8) o[(size_t)(n0+ty+j)*HH + k0+tx] = f2bf(t[tx][ty+j]);
}

// ---------------- fused QKV GEMM: phased, counted-vmcnt, 3-buffer ----------------
// 256x128 tile, BK=64, 512 thr (8 waves 2Mx4N, per-wave 128x32), prefetch dist 2.
// Per K-tile: 4 phases {ds_read frags | issue kt+2 loads | setprio-MFMA | s_barrier},
// boundary: s_waitcnt vmcnt(6) + s_barrier (loads stay in flight across barriers).
#define QBM 256
#define QBN 128
#define QBK 64
__global__ __launch_bounds__(512) void k_qkv(const unsigned short* __restrict__ Xb,
                                             const unsigned short* __restrict__ Wt,
                                             const float* __restrict__ bq,
                                             const float* __restrict__ bk,
                                             const float* __restrict__ bv,
                                             unsigned short* __restrict__ q_ws,
                                             unsigned short* __restrict__ k_ws,
                                             unsigned short* __restrict__ vt_ws){
  __shared__ __align__(16) unsigned short As[3][QBM*QBK];   // 3 x 32 KB
  __shared__ __align__(16) unsigned short Bs[3][QBN*QBK];   // 3 x 16 KB
  int tid = threadIdx.x;
  int lane = tid & 63, wid = tid >> 6;
  int wr = wid >> 2, wc = wid & 3;          // 2M x 4N wave grid
  int bid = blockIdx.x;
  int sw = (bid & 7)*96 + (bid >> 3);       // XCD-bijective (768 = 8*96)
  int nt = sw % 24, mt = sw / 24;
  int m0 = mt*QBM, n0 = nt*QBN;
  int lr = lane & 15, g = lane >> 4;

  int srow = tid >> 3;
  int sch  = (tid & 7) ^ (srow & 7);

  const f32x4 zf = {0.f,0.f,0.f,0.f};
  f32x4 acc[8][2];
  #pragma unroll
  for(int a=0;a<8;a++){ acc[a][0] = zf; acc[a][1] = zf; }

  // stage helpers: issue order per tile is A it0,it1,it2,it3, B it0,it1 (uniform)
  #define STAGE_A(buf, kb, it) do{ \
    int row_ = (it)*64 + srow; int slot_ = (it)*512 + tid; \
    gload_lds16(Xb + (size_t)(m0+row_)*1024 + (kb) + sch*8, &As[buf][slot_*8]); }while(0)
  #define STAGE_B(buf, kb, it) do{ \
    int row_ = (it)*64 + srow; int slot_ = (it)*512 + tid; \
    gload_lds16(Wt + (size_t)(n0+row_)*1024 + (kb) + sch*8, &Bs[buf][slot_*8]); }while(0)

  // prologue: issue tiles 0 and 1
  STAGE_A(0,0,0); STAGE_A(0,0,1); STAGE_A(0,0,2); STAGE_A(0,0,3);
  STAGE_B(0,0,0); STAGE_B(0,0,1);
  STAGE_A(1,QBK,0); STAGE_A(1,QBK,1); STAGE_A(1,QBK,2); STAGE_A(1,QBK,3);
  STAGE_B(1,QBK,0); STAGE_B(1,QBK,1);
  asm volatile("s_waitcnt vmcnt(6)" ::: "memory");   // tile 0 landed, tile 1 in flight
  __builtin_amdgcn_s_barrier();

  int cur = 0;
  for(int kt=0; kt<16; kt++){
    const unsigned short* Ab = As[cur];
    const unsigned short* Bb = Bs[cur];
    int nb = cur+2; if(nb>=3) nb-=3;        // dest buffer for kt+2
    bool pf = (kt < 14);
    int kb2 = (kt+2)*QBK;

    bf16x8 bfr[2], af[4];
    // ---- phase 0: ks=0, m-frags 0..3
    #pragma unroll
    for(int ni=0;ni<2;ni++){
      int r = wc*32 + ni*16 + lr;
      bfr[ni] = *(const bf16x8*)&Bb[r*64 + ((g ^ (r&7))<<3)];
    }
    #pragma unroll
    for(int mi=0;mi<4;mi++){
      int r = wr*128 + mi*16 + lr;
      af[mi] = *(const bf16x8*)&Ab[r*64 + ((g ^ (r&7))<<3)];
    }
    if(pf){ STAGE_A(nb,kb2,0); STAGE_A(nb,kb2,1); }
    __builtin_amdgcn_s_setprio(1);
    #pragma unroll
    for(int mi=0;mi<4;mi++)
      #pragma unroll
      for(int ni=0;ni<2;ni++)
        acc[mi][ni] = __builtin_amdgcn_mfma_f32_16x16x32_bf16(af[mi], bfr[ni], acc[mi][ni], 0,0,0);
    __builtin_amdgcn_s_setprio(0);
    __builtin_amdgcn_s_barrier();

    // ---- phase 1: ks=0, m-frags 4..7
    #pragma unroll
    for(int mi=0;mi<4;mi++){
      int r = wr*128 + (mi+4)*16 + lr;
      af[mi] = *(const bf16x8*)&Ab[r*64 + ((g ^ (r&7))<<3)];
    }
    if(pf){ STAGE_A(nb,kb2,2); STAGE_A(nb,kb2,3); }
    __builtin_amdgcn_s_setprio(1);
    #pragma unroll
    for(int mi=0;mi<4;mi++)
      #pragma unroll
      for(int ni=0;ni<2;ni++)
        acc[mi+4][ni] = __builtin_amdgcn_mfma_f32_16x16x32_bf16(af[mi], bfr[ni], acc[mi+4][ni], 0,0,0);
    __builtin_amdgcn_s_setprio(0);
    __builtin_amdgcn_s_barrier();

    // ---- phase 2: ks=1, m-frags 0..3
    #pragma unroll
    for(int ni=0;ni<2;ni++){
      int r = wc*32 + ni*16 + lr;
      bfr[ni] = *(const bf16x8*)&Bb[r*64 + (((4+g) ^ (r&7))<<3)];
    }
    #pragma unroll
    for(int mi=0;mi<4;mi++){
      int r = wr*128 + mi*16 + lr;
      af[mi] = *(const bf16x8*)&Ab[r*64 + (((4+g) ^ (r&7))<<3)];
    }
    if(pf){ STAGE_B(nb,kb2,0); STAGE_B(nb,kb2,1); }
    __builtin_amdgcn_s_setprio(1);
    #pragma unroll
    for(int mi=0;mi<4;mi++)
      #pragma unroll
      for(int ni=0;ni<2;ni++)
        acc[mi][ni] = __builtin_amdgcn_mfma_f32_16x16x32_bf16(af[mi], bfr[ni], acc[mi][ni], 0,0,0);
    __builtin_amdgcn_s_setprio(0);
    __builtin_amdgcn_s_barrier();

    // ---- phase 3: ks=1, m-frags 4..7
    #pragma unroll
    for(int mi=0;mi<4;mi++){
      int r = wr*128 + (mi+4)*16 + lr;
      af[mi] = *(const bf16x8*)&Ab[r*64 + (((4+g) ^ (r&7))<<3)];
    }
    __builtin_amdgcn_s_setprio(1);
    #pragma unroll
    for(int mi=0;mi<4;mi++)
      #pragma unroll
      for(int ni=0;ni<2;ni++)
        acc[mi+4][ni] = __builtin_amdgcn_mfma_f32_16x16x32_bf16(af[mi], bfr[ni], acc[mi+4][ni], 0,0,0);
    __builtin_amdgcn_s_setprio(0);

    // ---- tile boundary: counted wait (kt+1 landed, kt+2 stays in flight)
    if(kt < 14)       asm volatile("s_waitcnt vmcnt(6)" ::: "memory");
    else if(kt == 14) asm volatile("s_waitcnt vmcnt(0)" ::: "memory");
    __builtin_amdgcn_s_barrier();
    cur++; if(cur>=3) cur-=3;
  }
  #undef STAGE_A
  #undef STAGE_B

  // epilogue: row m = m0 + wr*128 + mi*16 + g*4 + i ; col n = n0 + wc*32 + ni*16 + lr
  int proj = n0 >> 10;
  const float* bias = (proj==0)?bq:((proj==1)?bk:bv);
  const float QSCALE = 0.18033688f;        // 0.125 * log2(e)
  #pragma unroll
  for(int mi=0;mi<8;mi++){
    #pragma unroll
    for(int ni=0;ni<2;ni++){
      int ncol = n0 + wc*32 + ni*16 + lr;
      int hcol = ncol & 1023;
      int h = hcol >> 6, d = hcol & 63;
      float bval = bias[hcol];
      if(proj == 0){
        #pragma unroll
        for(int i=0;i<4;i++){
          int m = m0 + wr*128 + mi*16 + g*4 + i;
          int b = m >> 10, s = m & 1023;
          q_ws[((size_t)(b*NH + h)*SQ + s)*HD + d] = f2bf((acc[mi][ni][i] + bval)*QSCALE);
        }
      } else if(proj == 1){
        #pragma unroll
        for(int i=0;i<4;i++){
          int m = m0 + wr*128 + mi*16 + g*4 + i;
          int b = m >> 10, s = m & 1023;
          k_ws[((size_t)(b*NH + h)*SQ + s)*HD + d] = f2bf(acc[mi][ni][i] + bval);
        }
      } else {
        int m = m0 + wr*128 + mi*16 + g*4;
        int b = m >> 10, s = m & 1023;
        u16x4 pk;
        #pragma unroll
        for(int i=0;i<4;i++) pk[i] = f2bf(acc[mi][ni][i] + bval);
        *(u16x4*)&vt_ws[((size_t)(b*NH + h)*HD + d)*SQ + s] = pk;
      }
    }
  }
}

// ---------------- flash attention: 32 q-rows/wave, swapped QK^T ----------------
__global__ __launch_bounds__(256) void k_attn(const unsigned short* __restrict__ q_ws,
                                              const unsigned short* __restrict__ k_ws,
                                              const unsigned short* __restrict__ vt_ws,
                                              float* __restrict__ out){
  __shared__ __align__(16) unsigned short Ks[2][64*64];
  __shared__ __align__(16) unsigned short Vs[2][64*64];
  __shared__ __align__(16) unsigned short Ps[4][32*64];
  int tid = threadIdx.x, lane = tid & 63, wid = tid >> 6;
  int lr = lane & 15, g = lane >> 4;
  int bid = blockIdx.x;
  int swz = (bid & 7)*128 + (bid >> 3);
  int qb = swz & 7, bh = swz >> 3;
  int qw = qb*128 + wid*32;
  const unsigned short* qp = q_ws + (size_t)bh*SQ*HD;
  const unsigned short* kp = k_ws + (size_t)bh*SQ*HD;
  const unsigned short* vp = vt_ws + (size_t)bh*HD*SQ;

  bf16x8 qf[2][2];
  #pragma unroll
  for(int ns=0;ns<2;ns++)
    #pragma unroll
    for(int ks=0;ks<2;ks++)
      qf[ns][ks] = *(const bf16x8*)&qp[(size_t)(qw + ns*16 + lr)*HD + ks*32 + g*8];

  int diag = qw >> 6;

  int srow = tid >> 3;
  int sch  = (tid & 7) ^ (srow & 7);

  const f32x4 zf = {0.f,0.f,0.f,0.f};
  float lacc[2] = {0.f, 0.f};
  f32x4 co[4][2];
  #pragma unroll
  for(int ms=0;ms<4;ms++)
    #pragma unroll
    for(int ns=0;ns<2;ns++) co[ms][ns] = zf;

  unsigned short* Pw = &Ps[wid][0];

  #pragma unroll
  for(int it=0; it<2; it++){
    int row = it*32 + srow, slot = it*256 + tid;
    gload_lds16(kp + (size_t)row*HD + sch*8, &Ks[0][slot*8]);
    gload_lds16(vp + (size_t)row*SQ + sch*8, &Vs[0][slot*8]);
  }
  __syncthreads();

  int cur = 0;
  for(int kt=0; kt<16; kt++){
    if(kt < 15){
      int kb = (kt+1)*64;
      #pragma unroll
      for(int it=0; it<2; it++){
        int row = it*32 + srow, slot = it*256 + tid;
        gload_lds16(kp + (size_t)(kb+row)*HD + sch*8, &Ks[cur^1][slot*8]);
        gload_lds16(vp + (size_t)row*SQ + kb + sch*8, &Vs[cur^1][slot*8]);
      }
    }

    f32x4 sc[4][2];
    #pragma unroll
    for(int ms=0;ms<4;ms++){
      int r = ms*16 + lr;
      bf16x8 kf0 = *(const bf16x8*)&Ks[cur][r*64 + ((g ^ (r&7))<<3)];
      bf16x8 kf1 = *(const bf16x8*)&Ks[cur][r*64 + (((4+g) ^ (r&7))<<3)];
      #pragma unroll
      for(int ns=0;ns<2;ns++){
        sc[ms][ns] = __builtin_amdgcn_mfma_f32_16x16x32_bf16(kf0, qf[ns][0], zf, 0,0,0);
        sc[ms][ns] = __builtin_amdgcn_mfma_f32_16x16x32_bf16(kf1, qf[ns][1], sc[ms][ns], 0,0,0);
      }
    }

    float add = (kt == diag) ? 0.72134752f : 0.0f;

    #pragma unroll
    for(int ms=0;ms<4;ms++){
      #pragma unroll
      for(int ns=0;ns<2;ns++){
        u16x4 pk;
        #pragma unroll
        for(int i=0;i<4;i++){
          float pv = __builtin_amdgcn_exp2f(sc[ms][ns][i] + add);
          lacc[ns] += pv;
          pk[i] = f2bf(pv);
        }
        int q = ns*16 + lr;
        int c = ms*2 + (g>>1);
        *(u16x4*)&Pw[q*64 + ((c ^ (q&7))<<3) + (g&1)*4] = pk;
      }
    }

    #pragma unroll
    for(int ms=0;ms<4;ms++){
      int vr = ms*16 + lr;
      bf16x8 vf0 = *(const bf16x8*)&Vs[cur][vr*64 + ((g ^ (vr&7))<<3)];
      bf16x8 vf1 = *(const bf16x8*)&Vs[cur][vr*64 + (((4+g) ^ (vr&7))<<3)];
      #pragma unroll
      for(int ns=0;ns<2;ns++){
        int q = ns*16 + lr;
        bf16x8 pf0 = *(const bf16x8*)&Pw[q*64 + ((g ^ (q&7))<<3)];
        bf16x8 pf1 = *(const bf16x8*)&Pw[q*64 + (((4+g) ^ (q&7))<<3)];
        co[ms][ns] = __builtin_amdgcn_mfma_f32_16x16x32_bf16(vf0, pf0, co[ms][ns], 0,0,0);
        co[ms][ns] = __builtin_amdgcn_mfma_f32_16x16x32_bf16(vf1, pf1, co[ms][ns], 0,0,0);
      }
    }

    __syncthreads();
    cur ^= 1;
  }

  float rl[2];
  #pragma unroll
  for(int ns=0;ns<2;ns++){
    float l = lacc[ns];
    l += __shfl_xor(l, 16);
    l += __shfl_xor(l, 32);
    rl[ns] = 1.0f / l;
  }
  int b = bh >> 4, h = bh & 15;
  #pragma unroll
  for(int ms=0;ms<4;ms++){
    #pragma unroll
    for(int ns=0;ns<2;ns++){
      int q = qw + ns*16 + lr;
      int d = h*HD + ms*16 + g*4;
      f32x4 r = co[ms][ns];
      r[0]*=rl[ns]; r[1]*=rl[ns]; r[2]*=rl[ns]; r[3]*=rl[ns];
      *(f32x4*)&out[((size_t)(b*SQ + q))*HH + d] = r;
    }
  }
}

extern "C" void kernel_launch(void* const* d_in, const int* in_sizes, int n_in,
                              void* d_out, int out_size, void* d_ws, size_t ws_size,
                              hipStream_t stream){
  const float* hs = (const float*)d_in[0];
  const float* Wq = (const float*)d_in[1];
  const float* bq = (const float*)d_in[2];
  const float* Wk = (const float*)d_in[3];
  const float* bk = (const float*)d_in[4];
  const float* Wv = (const float*)d_in[5];
  const float* bv = (const float*)d_in[6];
  float* out = (float*)d_out;

  unsigned char* ws = (unsigned char*)d_ws;
  const size_t NX = (size_t)8192*1024;
  unsigned short* xb    = (unsigned short*)ws;
  unsigned short* wt    = (unsigned short*)(ws + NX*2);
  unsigned short* q_ws  = (unsigned short*)(ws + NX*2 + (size_t)3*1024*1024*2);
  unsigned short* k_ws  = q_ws + NX;
  unsigned short* vt_ws = k_ws + NX;

  k_convert_x<<<4096, 256, 0, stream>>>(hs, xb);
  k_wt<<<dim3(32,32,3), dim3(32,8), 0, stream>>>(Wq, Wk, Wv, wt);
  k_qkv<<<768, 512, 0, stream>>>(xb, wt, bq, bk, bv, q_ws, k_ws, vt_ws);
  k_attn<<<1024, 256, 0, stream>>>(q_ws, k_ws, vt_ws, out);
}

// Round 6
// 223.556 us; speedup vs baseline: 1.0571x; 1.0571x over previous
//
#include <hip/hip_runtime.h>
#include <cstdint>

#define BB 8
#define SQ 1024
#define HH 1024
#define NH 16
#define HD 64

typedef __attribute__((ext_vector_type(4))) float f32x4;
typedef __attribute__((ext_vector_type(8))) __bf16 bf16x8;
typedef __attribute__((ext_vector_type(8))) unsigned short u16x8;
typedef __attribute__((ext_vector_type(4))) unsigned short u16x4;

__device__ __forceinline__ unsigned short f2bf(float f){
  uint32_t u = __builtin_bit_cast(uint32_t, f);
  u += 0x7FFFu + ((u >> 16) & 1u);
  return (unsigned short)(u >> 16);
}

__device__ __forceinline__ void gload_lds16(const void* g, void* l){
  __builtin_amdgcn_global_load_lds((__attribute__((address_space(1))) void*)g,
                                   (__attribute__((address_space(3))) void*)l,
                                   16, 0, 0);
}

// ---------------- fused prep: convert X fp32->bf16  +  W transpose/convert ----------------
// blocks [0,4096): convert 8 elems/thread of hidden_states
// blocks [4096,7168): one 32x32 transpose tile of Wq/Wk/Wv
__global__ __launch_bounds__(256) void k_prep(const float* __restrict__ x,
                                              unsigned short* __restrict__ xb,
                                              const float* __restrict__ Wq,
                                              const float* __restrict__ Wk,
                                              const float* __restrict__ Wv,
                                              unsigned short* __restrict__ wt){
  __shared__ float t[32][33];
  int bid = blockIdx.x, tid = threadIdx.x;
  if(bid < 4096){
    int i = bid * 256 + tid;
    const f32x4* xv = (const f32x4*)x;
    f32x4 a = xv[2*i], b = xv[2*i+1];
    u16x8 o;
    o[0]=f2bf(a[0]); o[1]=f2bf(a[1]); o[2]=f2bf(a[2]); o[3]=f2bf(a[3]);
    o[4]=f2bf(b[0]); o[5]=f2bf(b[1]); o[6]=f2bf(b[2]); o[7]=f2bf(b[3]);
    ((u16x8*)xb)[i] = o;
  } else {
    int idx = bid - 4096;
    int p = idx >> 10, rem = idx & 1023;
    const float* W = (p==0)?Wq:((p==1)?Wk:Wv);
    int n0 = (rem & 31)*32, k0 = (rem >> 5)*32;
    int tx = tid & 31, ty = tid >> 5;
    #pragma unroll
    for(int j=0;j<32;j+=8) t[ty+j][tx] = W[(size_t)(k0+ty+j)*HH + n0+tx];
    __syncthreads();
    unsigned short* o = wt + (size_t)p*HH*HH;
    #pragma unroll
    for(int j=0;j<32;j+=8) o[(size_t)(n0+ty+j)*HH + k0+tx] = f2bf(t[tx][ty+j]);
  }
}

// ---------------- fused QKV GEMM (round-2 structure: single-buffer, BK=64) ----------------
#define BM 128
#define BN 128
#define BK 64
__global__ __launch_bounds__(256) void k_qkv(const unsigned short* __restrict__ Xb,
                                             const unsigned short* __restrict__ Wt,
                                             const float* __restrict__ bq,
                                             const float* __restrict__ bk,
                                             const float* __restrict__ bv,
                                             unsigned short* __restrict__ q_ws,
                                             unsigned short* __restrict__ k_ws,
                                             unsigned short* __restrict__ vt_ws){
  __shared__ __align__(16) unsigned short As[BM*BK];
  __shared__ __align__(16) unsigned short Bs[BN*BK];
  int tid = threadIdx.x;
  int lane = tid & 63, wid = tid >> 6;
  int nt = blockIdx.x % 24, mt = blockIdx.x / 24;
  int m0 = mt*BM, n0 = nt*BN;
  int wm = (wid & 1)*64, wn = (wid >> 1)*64;
  int lr = lane & 15, g = lane >> 4;

  const f32x4 zf = {0.f,0.f,0.f,0.f};
  f32x4 acc[4][4];
  #pragma unroll
  for(int a=0;a<4;a++)
    #pragma unroll
    for(int b=0;b<4;b++) acc[a][b] = zf;

  for(int kk=0; kk<1024; kk+=BK){
    __syncthreads();                       // prior-iter reads done
    #pragma unroll
    for(int it=0; it<4; it++){
      int slot = it*256 + tid;             // 1024 x 16B for A (128 rows x 8 chunks)
      int row = slot >> 3, ch = (slot & 7) ^ (row & 7);
      gload_lds16(Xb + (size_t)(m0+row)*1024 + kk + ch*8, &As[slot*8]);
    }
    #pragma unroll
    for(int it=0; it<4; it++){
      int slot = it*256 + tid;
      int row = slot >> 3, ch = (slot & 7) ^ (row & 7);
      gload_lds16(Wt + (size_t)(n0+row)*1024 + kk + ch*8, &Bs[slot*8]);
    }
    __syncthreads();                       // staging complete

    #pragma unroll
    for(int ks=0; ks<2; ks++){
      bf16x8 af[4], bfr[4];
      #pragma unroll
      for(int mi=0;mi<4;mi++){
        int r = wm + mi*16 + lr;
        af[mi] = *(const bf16x8*)&As[r*64 + (((ks*4+g) ^ (r&7))<<3)];
      }
      #pragma unroll
      for(int ni=0;ni<4;ni++){
        int r = wn + ni*16 + lr;
        bfr[ni] = *(const bf16x8*)&Bs[r*64 + (((ks*4+g) ^ (r&7))<<3)];
      }
      #pragma unroll
      for(int mi=0;mi<4;mi++)
        #pragma unroll
        for(int ni=0;ni<4;ni++)
          acc[mi][ni] = __builtin_amdgcn_mfma_f32_16x16x32_bf16(af[mi], bfr[ni], acc[mi][ni], 0,0,0);
    }
  }

  // epilogue: C row = wm+mi*16+g*4+i, col = wn+ni*16+lr
  int proj = n0 >> 10;
  const float* bias = (proj==0)?bq:((proj==1)?bk:bv);
  const float QSCALE = 0.18033688f;        // 0.125 * log2(e)
  #pragma unroll
  for(int mi=0;mi<4;mi++){
    #pragma unroll
    for(int ni=0;ni<4;ni++){
      int ncol = n0 + wn + ni*16 + lr;
      int hcol = ncol & 1023;
      int h = hcol >> 6, d = hcol & 63;
      float bval = bias[hcol];
      if(proj == 0){
        #pragma unroll
        for(int i=0;i<4;i++){
          int m = m0 + wm + mi*16 + g*4 + i;
          int b = m >> 10, s = m & 1023;
          q_ws[((size_t)(b*NH + h)*SQ + s)*HD + d] = f2bf((acc[mi][ni][i] + bval)*QSCALE);
        }
      } else if(proj == 1){
        #pragma unroll
        for(int i=0;i<4;i++){
          int m = m0 + wm + mi*16 + g*4 + i;
          int b = m >> 10, s = m & 1023;
          k_ws[((size_t)(b*NH + h)*SQ + s)*HD + d] = f2bf(acc[mi][ni][i] + bval);
        }
      } else {
        int m = m0 + wm + mi*16 + g*4;
        int b = m >> 10, s = m & 1023;
        u16x4 pk;
        #pragma unroll
        for(int i=0;i<4;i++) pk[i] = f2bf(acc[mi][ni][i] + bval);
        *(u16x4*)&vt_ws[((size_t)(b*NH + h)*HD + d)*SQ + s] = pk;
      }
    }
  }
}

// ---------------- flash attention: 256 q-rows/block, 8 waves x 32 q ----------------
// Swapped QK^T (A=K, B=Q_reg); no-max softmax in log2 units (Q pre-scaled);
// diagonal 64-block gets +0.5*log2e. grid 512 = 128 bh x 4 q-tiles.
__global__ __launch_bounds__(512) void k_attn(const unsigned short* __restrict__ q_ws,
                                              const unsigned short* __restrict__ k_ws,
                                              const unsigned short* __restrict__ vt_ws,
                                              float* __restrict__ out){
  __shared__ __align__(16) unsigned short Ks[2][64*64];  // [token][d], chunk-swizzled
  __shared__ __align__(16) unsigned short Vs[2][64*64];  // [d][token], chunk-swizzled
  __shared__ __align__(16) unsigned short Ps[8][32*64];  // per-wave P [q][token], swizzled
  int tid = threadIdx.x, lane = tid & 63, wid = tid >> 6;
  int lr = lane & 15, g = lane >> 4;
  int bid = blockIdx.x;
  int swz = (bid & 7)*64 + (bid >> 3);     // XCD-bijective (512 = 8*64)
  int qb = swz & 3, bh = swz >> 2;
  int qw = qb*256 + wid*32;                // this wave's first q row
  const unsigned short* qp = q_ws + (size_t)bh*SQ*HD;
  const unsigned short* kp = k_ws + (size_t)bh*SQ*HD;
  const unsigned short* vp = vt_ws + (size_t)bh*HD*SQ;

  // Q register fragments (B-operand): qf[ns][ks] = Q[qw+ns*16+lr][ks*32+g*8 ..]
  bf16x8 qf[2][2];
  #pragma unroll
  for(int ns=0;ns<2;ns++)
    #pragma unroll
    for(int ks=0;ks<2;ks++)
      qf[ns][ks] = *(const bf16x8*)&qp[(size_t)(qw + ns*16 + lr)*HD + ks*32 + g*8];

  int diag = qw >> 6;                      // wave-uniform constituent block

  // staging: 512 threads x 16B covers one 64x64 bf16 tile exactly
  int srow = tid >> 3;                     // 0..63
  int sch  = (tid & 7) ^ (srow & 7);

  const f32x4 zf = {0.f,0.f,0.f,0.f};
  float lacc[2] = {0.f, 0.f};
  f32x4 co[4][2];                          // [d-sub][q-sub], ctx^T
  #pragma unroll
  for(int ms=0;ms<4;ms++)
    #pragma unroll
    for(int ns=0;ns<2;ns++) co[ms][ns] = zf;

  unsigned short* Pw = &Ps[wid][0];

  // prologue: stage tile 0
  gload_lds16(kp + (size_t)srow*HD + sch*8, &Ks[0][tid*8]);
  gload_lds16(vp + (size_t)srow*SQ + sch*8, &Vs[0][tid*8]);
  __syncthreads();

  int cur = 0;
  for(int kt=0; kt<16; kt++){
    if(kt < 15){
      int kb = (kt+1)*64;
      gload_lds16(kp + (size_t)(kb+srow)*HD + sch*8, &Ks[cur^1][tid*8]);
      gload_lds16(vp + (size_t)srow*SQ + kb + sch*8, &Vs[cur^1][tid*8]);
    }

    // QK^T (swapped): A = K-tile rows, B = Q registers
    f32x4 sc[4][2];
    #pragma unroll
    for(int ms=0;ms<4;ms++){
      int r = ms*16 + lr;
      bf16x8 kf0 = *(const bf16x8*)&Ks[cur][r*64 + ((g ^ (r&7))<<3)];
      bf16x8 kf1 = *(const bf16x8*)&Ks[cur][r*64 + (((4+g) ^ (r&7))<<3)];
      #pragma unroll
      for(int ns=0;ns<2;ns++){
        sc[ms][ns] = __builtin_amdgcn_mfma_f32_16x16x32_bf16(kf0, qf[ns][0], zf, 0,0,0);
        sc[ms][ns] = __builtin_amdgcn_mfma_f32_16x16x32_bf16(kf1, qf[ns][1], sc[ms][ns], 0,0,0);
      }
    }

    float add = (kt == diag) ? 0.72134752f : 0.0f;

    // P = exp2(S+add); pack 4 tokens (chunk-contiguous) -> one ds_write_b64
    #pragma unroll
    for(int ms=0;ms<4;ms++){
      #pragma unroll
      for(int ns=0;ns<2;ns++){
        u16x4 pk;
        #pragma unroll
        for(int i=0;i<4;i++){
          float pv = __builtin_amdgcn_exp2f(sc[ms][ns][i] + add);
          lacc[ns] += pv;
          pk[i] = f2bf(pv);
        }
        int q = ns*16 + lr;
        int c = ms*2 + (g>>1);             // token chunk index (t0 = ms*16+g*4)
        *(u16x4*)&Pw[q*64 + ((c ^ (q&7))<<3) + (g&1)*4] = pk;
      }
    }
    // per-wave buffer: wave-internal lgkmcnt orders write -> read (no barrier)

    // PV: ctx^T += Vt * P^T.  P fragments hoisted: 4 distinct reads only.
    bf16x8 pf[2][2];
    #pragma unroll
    for(int ns=0;ns<2;ns++){
      int q = ns*16 + lr;
      pf[ns][0] = *(const bf16x8*)&Pw[q*64 + ((g ^ (q&7))<<3)];
      pf[ns][1] = *(const bf16x8*)&Pw[q*64 + (((4+g) ^ (q&7))<<3)];
    }
    #pragma unroll
    for(int ms=0;ms<4;ms++){
      int vr = ms*16 + lr;
      bf16x8 vf0 = *(const bf16x8*)&Vs[cur][vr*64 + ((g ^ (vr&7))<<3)];
      bf16x8 vf1 = *(const bf16x8*)&Vs[cur][vr*64 + (((4+g) ^ (vr&7))<<3)];
      #pragma unroll
      for(int ns=0;ns<2;ns++){
        co[ms][ns] = __builtin_amdgcn_mfma_f32_16x16x32_bf16(vf0, pf[ns][0], co[ms][ns], 0,0,0);
        co[ms][ns] = __builtin_amdgcn_mfma_f32_16x16x32_bf16(vf1, pf[ns][1], co[ms][ns], 0,0,0);
      }
    }

    __syncthreads();   // all waves done with buf[cur]; next tile's staging drained
    cur ^= 1;
  }

  // row sums: lane covers tokens ms*16+g*4+i -> reduce across 16-lane groups
  float rl[2];
  #pragma unroll
  for(int ns=0;ns<2;ns++){
    float l = lacc[ns];
    l += __shfl_xor(l, 16);
    l += __shfl_xor(l, 32);
    rl[ns] = 1.0f / l;
  }
  int b = bh >> 4, h = bh & 15;
  #pragma unroll
  for(int ms=0;ms<4;ms++){
    #pragma unroll
    for(int ns=0;ns<2;ns++){
      int q = qw + ns*16 + lr;
      int d = h*HD + ms*16 + g*4;
      f32x4 r = co[ms][ns];
      r[0]*=rl[ns]; r[1]*=rl[ns]; r[2]*=rl[ns]; r[3]*=rl[ns];
      *(f32x4*)&out[((size_t)(b*SQ + q))*HH + d] = r;
    }
  }
}

extern "C" void kernel_launch(void* const* d_in, const int* in_sizes, int n_in,
                              void* d_out, int out_size, void* d_ws, size_t ws_size,
                              hipStream_t stream){
  const float* hs = (const float*)d_in[0];
  const float* Wq = (const float*)d_in[1];
  const float* bq = (const float*)d_in[2];
  const float* Wk = (const float*)d_in[3];
  const float* bk = (const float*)d_in[4];
  const float* Wv = (const float*)d_in[5];
  const float* bv = (const float*)d_in[6];
  float* out = (float*)d_out;

  unsigned char* ws = (unsigned char*)d_ws;
  const size_t NX = (size_t)8192*1024;
  unsigned short* xb    = (unsigned short*)ws;
  unsigned short* wt    = (unsigned short*)(ws + NX*2);
  unsigned short* q_ws  = (unsigned short*)(ws + NX*2 + (size_t)3*1024*1024*2);
  unsigned short* k_ws  = q_ws + NX;
  unsigned short* vt_ws = k_ws + NX;

  k_prep<<<7168, 256, 0, stream>>>(hs, xb, Wq, Wk, Wv, wt);
  k_qkv<<<24*64, 256, 0, stream>>>(xb, wt, bq, bk, bv, q_ws, k_ws, vt_ws);
  k_attn<<<512, 512, 0, stream>>>(q_ws, k_ws, vt_ws, out);
}

// Round 8
// 219.078 us; speedup vs baseline: 1.0787x; 1.0204x over previous
//
#include <hip/hip_runtime.h>
#include <cstdint>

#define BB 8
#define SQ 1024
#define HH 1024
#define NH 16
#define HD 64

typedef __attribute__((ext_vector_type(4))) float f32x4;
typedef __attribute__((ext_vector_type(16))) float f32x16;
typedef __attribute__((ext_vector_type(8))) __bf16 bf16x8;
typedef __attribute__((ext_vector_type(8))) unsigned short u16x8;
typedef __attribute__((ext_vector_type(4))) unsigned short u16x4;
typedef __attribute__((ext_vector_type(4))) unsigned int u32x4;

__device__ __forceinline__ unsigned short f2bf(float f){
  uint32_t u = __builtin_bit_cast(uint32_t, f);
  u += 0x7FFFu + ((u >> 16) & 1u);
  return (unsigned short)(u >> 16);
}

__device__ __forceinline__ void gload_lds16(const void* g, void* l){
  __builtin_amdgcn_global_load_lds((__attribute__((address_space(1))) void*)g,
                                   (__attribute__((address_space(3))) void*)l,
                                   16, 0, 0);
}

// ---------------- fused prep: convert X fp32->bf16  +  W transpose/convert ----------------
__global__ __launch_bounds__(256) void k_prep(const float* __restrict__ x,
                                              unsigned short* __restrict__ xb,
                                              const float* __restrict__ Wq,
                                              const float* __restrict__ Wk,
                                              const float* __restrict__ Wv,
                                              unsigned short* __restrict__ wt){
  __shared__ float t[32][33];
  int bid = blockIdx.x, tid = threadIdx.x;
  if(bid < 4096){
    int i = bid * 256 + tid;
    const f32x4* xv = (const f32x4*)x;
    f32x4 a = xv[2*i], b = xv[2*i+1];
    u16x8 o;
    o[0]=f2bf(a[0]); o[1]=f2bf(a[1]); o[2]=f2bf(a[2]); o[3]=f2bf(a[3]);
    o[4]=f2bf(b[0]); o[5]=f2bf(b[1]); o[6]=f2bf(b[2]); o[7]=f2bf(b[3]);
    ((u16x8*)xb)[i] = o;
  } else {
    int idx = bid - 4096;
    int p = idx >> 10, rem = idx & 1023;
    const float* W = (p==0)?Wq:((p==1)?Wk:Wv);
    int n0 = (rem & 31)*32, k0 = (rem >> 5)*32;
    int tx = tid & 31, ty = tid >> 5;
    #pragma unroll
    for(int j=0;j<32;j+=8) t[ty+j][tx] = W[(size_t)(k0+ty+j)*HH + n0+tx];
    __syncthreads();
    unsigned short* o = wt + (size_t)p*HH*HH;
    #pragma unroll
    for(int j=0;j<32;j+=8) o[(size_t)(n0+ty+j)*HH + k0+tx] = f2bf(t[tx][ty+j]);
  }
}

// ---------------- fused QKV GEMM (round-2 structure: single-buffer, BK=64) ----------------
#define BM 128
#define BN 128
#define BK 64
__global__ __launch_bounds__(256) void k_qkv(const unsigned short* __restrict__ Xb,
                                             const unsigned short* __restrict__ Wt,
                                             const float* __restrict__ bq,
                                             const float* __restrict__ bk,
                                             const float* __restrict__ bv,
                                             unsigned short* __restrict__ q_ws,
                                             unsigned short* __restrict__ k_ws,
                                             unsigned short* __restrict__ vt_ws){
  __shared__ __align__(16) unsigned short As[BM*BK];
  __shared__ __align__(16) unsigned short Bs[BN*BK];
  int tid = threadIdx.x;
  int lane = tid & 63, wid = tid >> 6;
  int nt = blockIdx.x % 24, mt = blockIdx.x / 24;
  int m0 = mt*BM, n0 = nt*BN;
  int wm = (wid & 1)*64, wn = (wid >> 1)*64;
  int lr = lane & 15, g = lane >> 4;

  const f32x4 zf = {0.f,0.f,0.f,0.f};
  f32x4 acc[4][4];
  #pragma unroll
  for(int a=0;a<4;a++)
    #pragma unroll
    for(int b=0;b<4;b++) acc[a][b] = zf;

  for(int kk=0; kk<1024; kk+=BK){
    __syncthreads();
    #pragma unroll
    for(int it=0; it<4; it++){
      int slot = it*256 + tid;
      int row = slot >> 3, ch = (slot & 7) ^ (row & 7);
      gload_lds16(Xb + (size_t)(m0+row)*1024 + kk + ch*8, &As[slot*8]);
    }
    #pragma unroll
    for(int it=0; it<4; it++){
      int slot = it*256 + tid;
      int row = slot >> 3, ch = (slot & 7) ^ (row & 7);
      gload_lds16(Wt + (size_t)(n0+row)*1024 + kk + ch*8, &Bs[slot*8]);
    }
    __syncthreads();

    #pragma unroll
    for(int ks=0; ks<2; ks++){
      bf16x8 af[4], bfr[4];
      #pragma unroll
      for(int mi=0;mi<4;mi++){
        int r = wm + mi*16 + lr;
        af[mi] = *(const bf16x8*)&As[r*64 + (((ks*4+g) ^ (r&7))<<3)];
      }
      #pragma unroll
      for(int ni=0;ni<4;ni++){
        int r = wn + ni*16 + lr;
        bfr[ni] = *(const bf16x8*)&Bs[r*64 + (((ks*4+g) ^ (r&7))<<3)];
      }
      #pragma unroll
      for(int mi=0;mi<4;mi++)
        #pragma unroll
        for(int ni=0;ni<4;ni++)
          acc[mi][ni] = __builtin_amdgcn_mfma_f32_16x16x32_bf16(af[mi], bfr[ni], acc[mi][ni], 0,0,0);
    }
  }

  int proj = n0 >> 10;
  const float* bias = (proj==0)?bq:((proj==1)?bk:bv);
  const float QSCALE = 0.18033688f;        // 0.125 * log2(e)
  #pragma unroll
  for(int mi=0;mi<4;mi++){
    #pragma unroll
    for(int ni=0;ni<4;ni++){
      int ncol = n0 + wn + ni*16 + lr;
      int hcol = ncol & 1023;
      int h = hcol >> 6, d = hcol & 63;
      float bval = bias[hcol];
      if(proj == 0){
        #pragma unroll
        for(int i=0;i<4;i++){
          int m = m0 + wm + mi*16 + g*4 + i;
          int b = m >> 10, s = m & 1023;
          q_ws[((size_t)(b*NH + h)*SQ + s)*HD + d] = f2bf((acc[mi][ni][i] + bval)*QSCALE);
        }
      } else if(proj == 1){
        #pragma unroll
        for(int i=0;i<4;i++){
          int m = m0 + wm + mi*16 + g*4 + i;
          int b = m >> 10, s = m & 1023;
          k_ws[((size_t)(b*NH + h)*SQ + s)*HD + d] = f2bf(acc[mi][ni][i] + bval);
        }
      } else {
        int m = m0 + wm + mi*16 + g*4;
        int b = m >> 10, s = m & 1023;
        u16x4 pk;
        #pragma unroll
        for(int i=0;i<4;i++) pk[i] = f2bf(acc[mi][ni][i] + bval);
        *(u16x4*)&vt_ws[((size_t)(b*NH + h)*HD + d)*SQ + s] = pk;
      }
    }
  }
}

// ---------------- flash attention v3: 32x32 MFMA, P in registers ----------------
// 8 waves x 32 q = 256 q-rows/block; grid 512 = 128 bh x 4 q-tiles.
// QK^T (swapped): S^T = mfma32(A=K, B=Q): lane holds col q=lane&31,
//   rows token = (reg&3)+8*(reg>>2)+4*(lane>>5) per 32-token block.
// P-fragments for PV built IN-REGISTER: pack reg-pairs to bf16x2 words, then
//   v_permlane32_swap pairs (0,2),(1,3),(4,6),(5,7) -> B-frag words where
//   lane (h=lane>>5) holds tokens 8h+{2j,2j+1}. Vt A-frags use the same
//   token(h,j)=8h+j map -> dot pairing consistent regardless of true k-order.
// No-max softmax in log2 units; diagonal 64-block bonus +0.5*log2e.
__global__ __launch_bounds__(512, 4) void k_attn(const unsigned short* __restrict__ q_ws,
                                                 const unsigned short* __restrict__ k_ws,
                                                 const unsigned short* __restrict__ vt_ws,
                                                 float* __restrict__ out){
  __shared__ __align__(16) unsigned short Ks[2][64*64];  // [token][d], chunk-swizzled
  __shared__ __align__(16) unsigned short Vs[2][64*64];  // [d][token], chunk-swizzled
  int tid = threadIdx.x, lane = tid & 63, wid = tid >> 6;
  int lq = lane & 31, h5 = lane >> 5;
  int bid = blockIdx.x;
  int swz = (bid & 7)*64 + (bid >> 3);     // XCD-bijective (512 = 8*64)
  int qb = swz & 3, bh = swz >> 2;
  int qw = qb*256 + wid*32;                // this wave's first q row
  const unsigned short* qp = q_ws + (size_t)bh*SQ*HD;
  const unsigned short* kp = k_ws + (size_t)bh*SQ*HD;
  const unsigned short* vp = vt_ws + (size_t)bh*HD*SQ;

  // Q B-frags: qf[dk]: lane holds Q[qw+lq][dk*16 + 8*h5 .. +8]
  bf16x8 qf[4];
  #pragma unroll
  for(int dk=0;dk<4;dk++)
    qf[dk] = *(const bf16x8*)&qp[(size_t)(qw + lq)*HD + dk*16 + h5*8];

  int diag = qw >> 6;                      // wave-uniform constituent block

  int srow = tid >> 3;                     // 0..63
  int sch  = (tid & 7) ^ (srow & 7);

  f32x16 co[2];
  #pragma unroll
  for(int db=0;db<2;db++)
    #pragma unroll
    for(int r=0;r<16;r++) co[db][r] = 0.f;
  float lacc = 0.f;

  // prologue: stage tile 0 (512 thr x 16B = one 64x64 bf16 tile each)
  gload_lds16(kp + (size_t)srow*HD + sch*8, &Ks[0][tid*8]);
  gload_lds16(vp + (size_t)srow*SQ + sch*8, &Vs[0][tid*8]);
  __syncthreads();

  int cur = 0;
  for(int kt=0; kt<16; kt++){
    if(kt < 15){
      int kb = (kt+1)*64;
      gload_lds16(kp + (size_t)(kb+srow)*HD + sch*8, &Ks[cur^1][tid*8]);
      gload_lds16(vp + (size_t)srow*SQ + kb + sch*8, &Vs[cur^1][tid*8]);
    }
    float add = (kt == diag) ? 0.72134752f : 0.0f;

    #pragma unroll
    for(int tb=0; tb<2; tb++){
      // QK^T over full d=64: 4 chained 32x32x16 MFMA
      f32x16 sc;
      #pragma unroll
      for(int r=0;r<16;r++) sc[r] = 0.f;
      int r0 = tb*32 + lq;
      #pragma unroll
      for(int dk=0;dk<4;dk++){
        bf16x8 kf = *(const bf16x8*)&Ks[cur][r0*64 + (((2*dk + h5) ^ (r0&7))<<3)];
        sc = __builtin_amdgcn_mfma_f32_32x32x16_bf16(kf, qf[dk], sc, 0,0,0);
      }
      // exp2 + pack reg-pairs -> 8 words (low = even reg = lower token row)
      unsigned int pk[8];
      #pragma unroll
      for(int w=0;w<8;w++){
        float lo = __builtin_amdgcn_exp2f(sc[2*w] + add);
        float hi = __builtin_amdgcn_exp2f(sc[2*w+1] + add);
        lacc += lo + hi;
        pk[w] = (unsigned int)f2bf(lo) | ((unsigned int)f2bf(hi) << 16);
      }
      // permlane32_swap: d.hi-lanes <-> s.lo-lanes
      asm volatile("v_permlane32_swap_b32 %0, %1" : "+v"(pk[0]), "+v"(pk[2]));
      asm volatile("v_permlane32_swap_b32 %0, %1" : "+v"(pk[1]), "+v"(pk[3]));
      asm volatile("v_permlane32_swap_b32 %0, %1" : "+v"(pk[4]), "+v"(pk[6]));
      asm volatile("v_permlane32_swap_b32 %0, %1" : "+v"(pk[5]), "+v"(pk[7]));
      u32x4 w0 = {pk[0], pk[1], pk[2], pk[3]};   // kslice 2*tb   (tokens tb*32+0..15)
      u32x4 w1 = {pk[4], pk[5], pk[6], pk[7]};   // kslice 2*tb+1 (tokens tb*32+16..31)
      bf16x8 pf0 = __builtin_bit_cast(bf16x8, w0);
      bf16x8 pf1 = __builtin_bit_cast(bf16x8, w1);

      // PV: ctx^T[d][q] += Vt[d][tok] * P^T[tok][q]
      #pragma unroll
      for(int db=0;db<2;db++){
        int vr = db*32 + lq;
        bf16x8 vf0 = *(const bf16x8*)&Vs[cur][vr*64 + (((4*tb + h5) ^ (vr&7))<<3)];
        co[db] = __builtin_amdgcn_mfma_f32_32x32x16_bf16(vf0, pf0, co[db], 0,0,0);
        bf16x8 vf1 = *(const bf16x8*)&Vs[cur][vr*64 + (((4*tb + 2 + h5) ^ (vr&7))<<3)];
        co[db] = __builtin_amdgcn_mfma_f32_32x32x16_bf16(vf1, pf1, co[db], 0,0,0);
      }
    }

    __syncthreads();   // all waves done with buf[cur]; next tile's staging drained
    cur ^= 1;
  }

  // row sum: lanes l and l+32 hold complementary token rows for the same q
  lacc += __shfl_xor(lacc, 32);
  float rl = 1.0f / lacc;

  int b = bh >> 4, h = bh & 15;
  size_t obase = ((size_t)(b*SQ + qw + lq))*HH + h*HD;
  #pragma unroll
  for(int db=0;db<2;db++){
    #pragma unroll
    for(int w=0;w<4;w++){
      // regs 4w..4w+3 -> d = db*32 + 8w + 4*h5 + {0..3}
      f32x4 r;
      r[0] = co[db][4*w  ] * rl;
      r[1] = co[db][4*w+1] * rl;
      r[2] = co[db][4*w+2] * rl;
      r[3] = co[db][4*w+3] * rl;
      *(f32x4*)&out[obase + db*32 + 8*w + 4*h5] = r;
    }
  }
}

extern "C" void kernel_launch(void* const* d_in, const int* in_sizes, int n_in,
                              void* d_out, int out_size, void* d_ws, size_t ws_size,
                              hipStream_t stream){
  const float* hs = (const float*)d_in[0];
  const float* Wq = (const float*)d_in[1];
  const float* bq = (const float*)d_in[2];
  const float* Wk = (const float*)d_in[3];
  const float* bk = (const float*)d_in[4];
  const float* Wv = (const float*)d_in[5];
  const float* bv = (const float*)d_in[6];
  float* out = (float*)d_out;

  unsigned char* ws = (unsigned char*)d_ws;
  const size_t NX = (size_t)8192*1024;
  unsigned short* xb    = (unsigned short*)ws;
  unsigned short* wt    = (unsigned short*)(ws + NX*2);
  unsigned short* q_ws  = (unsigned short*)(ws + NX*2 + (size_t)3*1024*1024*2);
  unsigned short* k_ws  = q_ws + NX;
  unsigned short* vt_ws = k_ws + NX;

  k_prep<<<7168, 256, 0, stream>>>(hs, xb, Wq, Wk, Wv, wt);
  k_qkv<<<24*64, 256, 0, stream>>>(xb, wt, bq, bk, bv, q_ws, k_ws, vt_ws);
  k_attn<<<512, 512, 0, stream>>>(q_ws, k_ws, vt_ws, out);
}